// Round 13
// baseline (247.367 us; speedup 1.0000x reference)
//
#include <hip/hip_runtime.h>
#include <hip/hip_bf16.h>
#include <math.h>

// ---------- types ----------
typedef __bf16 bf16x8 __attribute__((ext_vector_type(8)));
typedef float  f32x4  __attribute__((ext_vector_type(4)));
typedef float  f32x16 __attribute__((ext_vector_type(16)));

#define B_ROWS 8192
#define HSZ    1024

#define GLOAD16(gsrc, ldst)                                                          \
  __builtin_amdgcn_global_load_lds((const __attribute__((address_space(1))) void*)(gsrc), \
                                   (__attribute__((address_space(3))) void*)(ldst),  \
                                   16, 0, 0)

__device__ inline unsigned short f2bf(float f) {
  union { float f; unsigned u; } x; x.f = f;
  unsigned r = x.u + 0x7fffu + ((x.u >> 16) & 1u);   // RNE
  return (unsigned short)(r >> 16);
}

__device__ inline float sigm(float x) { return 1.0f / (1.0f + __expf(-x)); }

// ---------- kernel 0: fp32 -> bf16 conversion + T precompute (16B stores) ----------
__global__ void k_convert(const float* __restrict__ inp,   // [8192][1025]
                          const float* __restrict__ h,     // [8192][1024]
                          const float* __restrict__ Wl,    // [4096][2048]
                          const float* __restrict__ Wd,    // [1024][1024]
                          unsigned short* __restrict__ comb, // [8192][2048]
                          unsigned short* __restrict__ Wlb,  // [4096][2048]
                          unsigned short* __restrict__ hb,   // [8192][1024]
                          unsigned short* __restrict__ Wdb,  // [1024][1024]
                          float* __restrict__ Tm1) {         // [8192] = T-1
  const long stride = (long)gridDim.x * blockDim.x;
  const long tid0 = (long)blockIdx.x * blockDim.x + threadIdx.x;

#define CNV8(dst, s0, s1) { ushort4 u0, u1;                                   \
    u0.x = f2bf(s0.x); u0.y = f2bf(s0.y); u0.z = f2bf(s0.z); u0.w = f2bf(s0.w); \
    u1.x = f2bf(s1.x); u1.y = f2bf(s1.y); u1.z = f2bf(s1.z); u1.w = f2bf(s1.w); \
    *(ushort4*)(dst) = u0; *(ushort4*)((dst) + 4) = u1; }

  for (long i = tid0; i < (long)B_ROWS * HSZ / 8; i += stride) {
    float4 v0 = ((const float4*)h)[i * 2], v1 = ((const float4*)h)[i * 2 + 1];
    CNV8(hb + i * 8, v0, v1);
  }
  for (long i = tid0; i < (long)B_ROWS * HSZ / 8; i += stride) {
    long e = i * 8; long b = e >> 10; long c = e & 1023;
    const float* s = inp + b * 1025 + c;
    float4 v0 = *(const float4*)s, v1 = *(const float4*)(s + 4);
    CNV8(comb + b * 2048 + c, v0, v1);
  }
  for (long i = tid0; i < 4096L * 2048 / 8; i += stride) {
    float4 v0 = ((const float4*)Wl)[i * 2], v1 = ((const float4*)Wl)[i * 2 + 1];
    CNV8(Wlb + i * 8, v0, v1);
  }
  for (long i = tid0; i < 1024L * 1024 / 8; i += stride) {
    float4 v0 = ((const float4*)Wd)[i * 2], v1 = ((const float4*)Wd)[i * 2 + 1];
    CNV8(Wdb + i * 8, v0, v1);
  }
  for (long i = tid0; i < B_ROWS; i += stride) {
    float dt = inp[i * 1025 + 1024];
    Tm1[i] = 1.0f / logf(dt + 2.7183f) - 1.0f;
  }
#undef CNV8
}

// ---------- kernel 1: C_ST GEMM (8192x1024x1024) + h_adj epilogue (known-good R3) ----------
__global__ void k_gemm1(const unsigned short* __restrict__ A,   // hb  [8192][1024]
                        const unsigned short* __restrict__ Bm,  // Wdb [1024][1024]
                        const float* __restrict__ h,            // h_cur f32
                        const float* __restrict__ bd,           // b_desc [1024]
                        const float* __restrict__ Tm1,
                        unsigned short* __restrict__ comb) {
  const int K = 1024;
  __shared__ __align__(16) unsigned short As[128 * 32];
  __shared__ __align__(16) unsigned short Bs[128 * 32];
  const int tid = threadIdx.x;
  const int lane = tid & 63;
  const int wave = tid >> 6;
  const int wr = wave >> 1, wc = wave & 1;
  const int bRow = blockIdx.x;    // 0..63
  const int bCol = blockIdx.y;    // 0..7

  const int sRow = tid >> 2;
  const int sK = (tid & 3) * 8;
  const unsigned short* aSrc0 = A + (long)(bRow * 128 + sRow) * K + sK;
  const unsigned short* aSrc1 = A + (long)(bRow * 128 + 64 + sRow) * K + sK;
  const unsigned short* bSrc0 = Bm + (long)(bCol * 128 + sRow) * K + sK;
  const unsigned short* bSrc1 = Bm + (long)(bCol * 128 + 64 + sRow) * K + sK;
  unsigned short* aDst0 = As + tid * 8;
  unsigned short* aDst1 = As + 2048 + tid * 8;
  unsigned short* bDst0 = Bs + tid * 8;
  unsigned short* bDst1 = Bs + 2048 + tid * 8;

  f32x4 acc[4][4] = {};
  const int fr = lane & 15, fk = (lane >> 4) * 8;

  for (int k0 = 0; k0 < K; k0 += 32) {
    GLOAD16(aSrc0 + k0, aDst0);
    GLOAD16(aSrc1 + k0, aDst1);
    GLOAD16(bSrc0 + k0, bDst0);
    GLOAD16(bSrc1 + k0, bDst1);
    __syncthreads();
    bf16x8 a[4], b[4];
#pragma unroll
    for (int m = 0; m < 4; m++) a[m] = *(const bf16x8*)(As + (wr * 64 + m * 16 + fr) * 32 + fk);
#pragma unroll
    for (int n = 0; n < 4; n++) b[n] = *(const bf16x8*)(Bs + (wc * 64 + n * 16 + fr) * 32 + fk);
#pragma unroll
    for (int m = 0; m < 4; m++)
#pragma unroll
      for (int n = 0; n < 4; n++)
        acc[m][n] = __builtin_amdgcn_mfma_f32_16x16x32_bf16(a[m], b[n], acc[m][n], 0, 0, 0);
    __syncthreads();
  }

  const int cr = (lane >> 4) * 4;
  const int cc = lane & 15;
#pragma unroll
  for (int m = 0; m < 4; m++)
#pragma unroll
    for (int n = 0; n < 4; n++) {
      const int col = bCol * 128 + wc * 64 + n * 16 + cc;
#pragma unroll
      for (int r = 0; r < 4; r++) {
        const int row = bRow * 128 + wr * 64 + m * 16 + cr + r;
        float v = acc[m][n][r] + bd[col];
        float cst = tanhf(v);
        float hadj = h[(long)row * HSZ + col] + Tm1[row] * cst;
        comb[(long)row * 2048 + 1024 + col] = f2bf(hadj);
      }
    }
}

// ---------- kernel 2: gates GEMM, 256-row x (64j x 4gate), 32x32x16 MFMA ----------
// R13: switch to v_mfma_f32_32x32x16_bf16 (measured ~20% faster/FLOP, half the
// MFMA instr count; identical LDS bytes). Wave = 64 rows x 4 gate-tiles(32 j each);
// acc[mt][g] (f32x16), frag g == gate -> fused LSTM epilogue kept.
// Schedule = R11 free-running: one "memory" vmcnt + one s_barrier per K32-tile,
// open region {stage t+3; 12 ds_reads; 16 MFMA}. Ring-4, ledger vmcnt(8)/tail 8,4,0.
// A/B operand layout: lane l -> row/col = l&31, k = 8*(l>>5)+i (ext of verified 16x16).
// C/D (m74/m101): col = lane&31, row = (reg&3) + 8*(reg>>2) + 4*(lane>>5).
#define NT2 64   // 2048/32
__global__ __launch_bounds__(512, 2)
void k_gemm2_32(const unsigned short* __restrict__ A,   // comb [8192][2048]
                const unsigned short* __restrict__ Bm,  // Wlb  [4096][2048]
                const float* __restrict__ bl,           // b_layers [4096]
                const float* __restrict__ c_cur,        // f32 [8192][1024]
                float* __restrict__ out) {              // h_next | c_next (f32)
  __shared__ __align__(16) unsigned short lds[4][16384];  // [A 256x32 | B 256x32] per slot

  const int tid = threadIdx.x;
  const int lane = tid & 63;
  const int wid = tid >> 6;
  const int wr = wid >> 1;          // 0..3 : 64-row group
  const int wc = wid & 1;           // 0..1 : 32-j half

  // L2-aware XCD mapping (R6)
  const int bid = blockIdx.x;
  const int xcd = bid & 7;
  const int ii = bid >> 3;
  const int sweep = ii >> 5;
  const int pos = ii & 31;
  const int bRow = xcd * 4 + sweep * 2 + (pos & 1);   // 0..31
  const int bCol = pos >> 1;                          // 0..15

  // ---- staging (pre-swizzled global source; LDS dest linear) ----
  const int sr = tid >> 2;                 // 0..127
  const int swsel = (sr >> 1) & 3;         // == swz(sr) == swz(sr+128)
  const int gk = ((tid & 3) ^ swsel) << 3;
  const unsigned short* aBase = A + (long)(bRow * 256 + sr) * 2048 + gk;
  // B local row rl -> gate = rl>>6, jl = rl&63 -> W row = gate*1024 + bCol*64 + jl
  const int grow0 = (sr >> 6) * 1024 + bCol * 64 + (sr & 63);         // rl = sr
  const int grow1 = (2 + (sr >> 6)) * 1024 + bCol * 64 + (sr & 63);   // rl = 128+sr
  const unsigned short* bBase0 = Bm + (long)grow0 * 2048 + gk;
  const unsigned short* bBase1 = Bm + (long)grow1 * 2048 + gk;

#define STAGE_A2(slot, tt) { unsigned short* d_ = &lds[slot][0] + tid * 8;        \
    GLOAD16(aBase + (long)(tt) * 32, d_);                                          \
    GLOAD16(aBase + 128L * 2048 + (long)(tt) * 32, d_ + 4096); }
#define STAGE_B2(slot, tt) { unsigned short* d_ = &lds[slot][8192] + tid * 8;     \
    GLOAD16(bBase0 + (long)(tt) * 32, d_);                                         \
    GLOAD16(bBase1 + (long)(tt) * 32, d_ + 4096); }

  // ---- fragment read offsets (swizzled), ushort units ----
  int offA[2][2], offB[4][2];
#pragma unroll
  for (int mt = 0; mt < 2; mt++)
#pragma unroll
    for (int ks = 0; ks < 2; ks++) {
      const int row = wr * 64 + mt * 32 + (lane & 31);
      offA[mt][ks] = row * 32 + (((2 * ks + (lane >> 5)) ^ ((row >> 1) & 3)) << 3);
    }
#pragma unroll
  for (int g = 0; g < 4; g++)
#pragma unroll
    for (int ks = 0; ks < 2; ks++) {
      const int rl = g * 64 + wc * 32 + (lane & 31);
      offB[g][ks] = 8192 + rl * 32 + (((2 * ks + (lane >> 5)) ^ ((rl >> 1) & 3)) << 3);
    }

  f32x16 acc[2][4] = {};   // [mt][gate]

  // ---- prologue: stage tiles 0,1,2 into slots 0,1,2 ----
  STAGE_A2(0, 0); STAGE_B2(0, 0);
  STAGE_A2(1, 1); STAGE_B2(1, 1);
  STAGE_A2(2, 2); STAGE_B2(2, 2);

#define BODY(t, SLOT, VM, DOSTAGE)                                                   \
  {                                                                                  \
    asm volatile("s_waitcnt vmcnt(" #VM ")" ::: "memory");                           \
    __builtin_amdgcn_s_barrier();                                                    \
    if (DOSTAGE) { STAGE_A2(((t) + 3) & 3, (t) + 3); STAGE_B2(((t) + 3) & 3, (t) + 3); } \
    const unsigned short* buf = &lds[SLOT][0];                                       \
    bf16x8 aF[2][2], bF[4][2];                                                       \
    _Pragma("unroll")                                                                \
    for (int g = 0; g < 4; g++) {                                                    \
      bF[g][0] = *(const bf16x8*)(buf + offB[g][0]);                                 \
      bF[g][1] = *(const bf16x8*)(buf + offB[g][1]);                                 \
    }                                                                                \
    _Pragma("unroll")                                                                \
    for (int mt = 0; mt < 2; mt++) {                                                 \
      aF[mt][0] = *(const bf16x8*)(buf + offA[mt][0]);                               \
      aF[mt][1] = *(const bf16x8*)(buf + offA[mt][1]);                               \
    }                                                                                \
    __builtin_amdgcn_s_setprio(1);                                                   \
    _Pragma("unroll")                                                                \
    for (int mt = 0; mt < 2; mt++)                                                   \
      _Pragma("unroll")                                                              \
      for (int g = 0; g < 4; g++) {                                                  \
        acc[mt][g] = __builtin_amdgcn_mfma_f32_32x32x16_bf16(aF[mt][0], bF[g][0], acc[mt][g], 0, 0, 0); \
        acc[mt][g] = __builtin_amdgcn_mfma_f32_32x32x16_bf16(aF[mt][1], bF[g][1], acc[mt][g], 0, 0, 0); \
      }                                                                              \
    __builtin_amdgcn_s_setprio(0);                                                   \
  }

  for (int t = 0; t < 60; t += 4) {
    BODY(t,     0, 8, true);
    BODY(t + 1, 1, 8, true);
    BODY(t + 2, 2, 8, true);
    BODY(t + 3, 3, 8, true);
  }
  BODY(60, 0, 8, true);
  BODY(61, 1, 8, false);
  BODY(62, 2, 4, false);
  BODY(63, 3, 0, false);
#undef BODY

  // ---- fused LSTM epilogue (32x32 C/D layout) ----
  const int j = bCol * 64 + wc * 32 + (lane & 31);   // one j for all 4 gates
  const int rb = (lane >> 5) * 4;
  const float bl0 = bl[j], bl1 = bl[1024 + j], bl2 = bl[2048 + j], bl3 = bl[3072 + j];
#pragma unroll
  for (int mt = 0; mt < 2; mt++) {
#pragma unroll
    for (int r = 0; r < 16; r++) {
      const int row = bRow * 256 + wr * 64 + mt * 32 + (r & 3) + 8 * (r >> 2) + rb;
      float iv = sigm(acc[mt][0][r] + bl0);
      float fv = sigm(acc[mt][1][r] + bl1);
      float ov = sigm(acc[mt][2][r] + bl2);
      float gv = tanhf(acc[mt][3][r] + bl3);
      float cn = fv * c_cur[(long)row * HSZ + j] + iv * gv;
      float hn = ov * tanhf(cn);
      out[(long)row * HSZ + j] = hn;                         // h_next
      out[(long)B_ROWS * HSZ + (long)row * HSZ + j] = cn;    // c_next
    }
  }
}

// ---------- launch ----------
extern "C" void kernel_launch(void* const* d_in, const int* in_sizes, int n_in,
                              void* d_out, int out_size, void* d_ws, size_t ws_size,
                              hipStream_t stream) {
  const float* inp = (const float*)d_in[0];   // input_tensor [8192][1025]
  const float* h   = (const float*)d_in[1];   // h_cur
  const float* c   = (const float*)d_in[2];   // c_cur
  const float* Wl  = (const float*)d_in[3];   // W_layers [4096][2048]
  const float* bl  = (const float*)d_in[4];   // b_layers [4096]
  const float* Wd  = (const float*)d_in[5];   // W_desc [1024][1024]
  const float* bd  = (const float*)d_in[6];   // b_desc [1024]

  char* ws = (char*)d_ws;
  unsigned short* comb = (unsigned short*)(ws);               // 33,554,432 B
  unsigned short* Wlb  = (unsigned short*)(ws + 33554432);    // 16,777,216 B
  unsigned short* hb   = (unsigned short*)(ws + 50331648);    // 16,777,216 B
  unsigned short* Wdb  = (unsigned short*)(ws + 67108864);    //  2,097,152 B
  float*          Tm1  = (float*)(ws + 69206016);             //     32,768 B
  float*          out  = (float*)d_out;                       // f32 outputs

  hipLaunchKernelGGL(k_convert, dim3(2048), dim3(256), 0, stream,
                     inp, h, Wl, Wd, comb, Wlb, hb, Wdb, Tm1);
  hipLaunchKernelGGL(k_gemm1, dim3(64, 8), dim3(256), 0, stream,
                     hb, Wdb, h, bd, Tm1, comb);
  hipLaunchKernelGGL(k_gemm2_32, dim3(512), dim3(512), 0, stream,
                     comb, Wlb, bl, c, out);
}

// Round 14
// 228.105 us; speedup vs baseline: 1.0844x; 1.0844x over previous
//
#include <hip/hip_runtime.h>
#include <hip/hip_bf16.h>
#include <math.h>

// ---------- types ----------
typedef __bf16 bf16x8 __attribute__((ext_vector_type(8)));
typedef float  f32x4  __attribute__((ext_vector_type(4)));

#define B_ROWS 8192
#define HSZ    1024

#define GLOAD16(gsrc, ldst)                                                          \
  __builtin_amdgcn_global_load_lds((const __attribute__((address_space(1))) void*)(gsrc), \
                                   (__attribute__((address_space(3))) void*)(ldst),  \
                                   16, 0, 0)

__device__ inline unsigned short f2bf(float f) {
  union { float f; unsigned u; } x; x.f = f;
  unsigned r = x.u + 0x7fffu + ((x.u >> 16) & 1u);   // RNE
  return (unsigned short)(r >> 16);
}

__device__ inline float sigm(float x) { return 1.0f / (1.0f + __expf(-x)); }

// ---------- kernel 0: fp32 -> bf16 conversion + T precompute (16B stores) ----------
__global__ void k_convert(const float* __restrict__ inp,   // [8192][1025]
                          const float* __restrict__ h,     // [8192][1024]
                          const float* __restrict__ Wl,    // [4096][2048]
                          const float* __restrict__ Wd,    // [1024][1024]
                          unsigned short* __restrict__ comb, // [8192][2048]
                          unsigned short* __restrict__ Wlb,  // [4096][2048]
                          unsigned short* __restrict__ hb,   // [8192][1024]
                          unsigned short* __restrict__ Wdb,  // [1024][1024]
                          float* __restrict__ Tm1) {         // [8192] = T-1
  const long stride = (long)gridDim.x * blockDim.x;
  const long tid0 = (long)blockIdx.x * blockDim.x + threadIdx.x;

#define CNV8(dst, s0, s1) { ushort4 u0, u1;                                   \
    u0.x = f2bf(s0.x); u0.y = f2bf(s0.y); u0.z = f2bf(s0.z); u0.w = f2bf(s0.w); \
    u1.x = f2bf(s1.x); u1.y = f2bf(s1.y); u1.z = f2bf(s1.z); u1.w = f2bf(s1.w); \
    *(ushort4*)(dst) = u0; *(ushort4*)((dst) + 4) = u1; }

  for (long i = tid0; i < (long)B_ROWS * HSZ / 8; i += stride) {
    float4 v0 = ((const float4*)h)[i * 2], v1 = ((const float4*)h)[i * 2 + 1];
    CNV8(hb + i * 8, v0, v1);
  }
  for (long i = tid0; i < (long)B_ROWS * HSZ / 8; i += stride) {
    long e = i * 8; long b = e >> 10; long c = e & 1023;
    const float* s = inp + b * 1025 + c;
    float4 v0 = *(const float4*)s, v1 = *(const float4*)(s + 4);
    CNV8(comb + b * 2048 + c, v0, v1);
  }
  for (long i = tid0; i < 4096L * 2048 / 8; i += stride) {
    float4 v0 = ((const float4*)Wl)[i * 2], v1 = ((const float4*)Wl)[i * 2 + 1];
    CNV8(Wlb + i * 8, v0, v1);
  }
  for (long i = tid0; i < 1024L * 1024 / 8; i += stride) {
    float4 v0 = ((const float4*)Wd)[i * 2], v1 = ((const float4*)Wd)[i * 2 + 1];
    CNV8(Wdb + i * 8, v0, v1);
  }
  for (long i = tid0; i < B_ROWS; i += stride) {
    float dt = inp[i * 1025 + 1024];
    Tm1[i] = 1.0f / logf(dt + 2.7183f) - 1.0f;
  }
#undef CNV8
}

// ---------- kernel 1: C_ST GEMM (8192x1024x1024) + h_adj epilogue (known-good R3) ----------
__global__ void k_gemm1(const unsigned short* __restrict__ A,   // hb  [8192][1024]
                        const unsigned short* __restrict__ Bm,  // Wdb [1024][1024]
                        const float* __restrict__ h,            // h_cur f32
                        const float* __restrict__ bd,           // b_desc [1024]
                        const float* __restrict__ Tm1,
                        unsigned short* __restrict__ comb) {
  const int K = 1024;
  __shared__ __align__(16) unsigned short As[128 * 32];
  __shared__ __align__(16) unsigned short Bs[128 * 32];
  const int tid = threadIdx.x;
  const int lane = tid & 63;
  const int wave = tid >> 6;
  const int wr = wave >> 1, wc = wave & 1;
  const int bRow = blockIdx.x;    // 0..63
  const int bCol = blockIdx.y;    // 0..7

  const int sRow = tid >> 2;
  const int sK = (tid & 3) * 8;
  const unsigned short* aSrc0 = A + (long)(bRow * 128 + sRow) * K + sK;
  const unsigned short* aSrc1 = A + (long)(bRow * 128 + 64 + sRow) * K + sK;
  const unsigned short* bSrc0 = Bm + (long)(bCol * 128 + sRow) * K + sK;
  const unsigned short* bSrc1 = Bm + (long)(bCol * 128 + 64 + sRow) * K + sK;
  unsigned short* aDst0 = As + tid * 8;
  unsigned short* aDst1 = As + 2048 + tid * 8;
  unsigned short* bDst0 = Bs + tid * 8;
  unsigned short* bDst1 = Bs + 2048 + tid * 8;

  f32x4 acc[4][4] = {};
  const int fr = lane & 15, fk = (lane >> 4) * 8;

  for (int k0 = 0; k0 < K; k0 += 32) {
    GLOAD16(aSrc0 + k0, aDst0);
    GLOAD16(aSrc1 + k0, aDst1);
    GLOAD16(bSrc0 + k0, bDst0);
    GLOAD16(bSrc1 + k0, bDst1);
    __syncthreads();
    bf16x8 a[4], b[4];
#pragma unroll
    for (int m = 0; m < 4; m++) a[m] = *(const bf16x8*)(As + (wr * 64 + m * 16 + fr) * 32 + fk);
#pragma unroll
    for (int n = 0; n < 4; n++) b[n] = *(const bf16x8*)(Bs + (wc * 64 + n * 16 + fr) * 32 + fk);
#pragma unroll
    for (int m = 0; m < 4; m++)
#pragma unroll
      for (int n = 0; n < 4; n++)
        acc[m][n] = __builtin_amdgcn_mfma_f32_16x16x32_bf16(a[m], b[n], acc[m][n], 0, 0, 0);
    __syncthreads();
  }

  const int cr = (lane >> 4) * 4;
  const int cc = lane & 15;
#pragma unroll
  for (int m = 0; m < 4; m++)
#pragma unroll
    for (int n = 0; n < 4; n++) {
      const int col = bCol * 128 + wc * 64 + n * 16 + cc;
#pragma unroll
      for (int r = 0; r < 4; r++) {
        const int row = bRow * 128 + wr * 64 + m * 16 + cr + r;
        float v = acc[m][n][r] + bd[col];
        float cst = tanhf(v);
        float hadj = h[(long)row * HSZ + col] + Tm1[row] * cst;
        comb[(long)row * 2048 + 1024 + col] = f2bf(hadj);
      }
    }
}

// ---------- kernel 2: gates GEMM, 256x256, ring-4, WIDE-WINDOW sync (per-2-tile drain) ----------
// R14: sync convergence every 2 tiles instead of every tile. Ring-4 slots ping-pong in
// GROUPS of 2 ({0,1} <-> {2,3}): interval computes tiles {t,t+1} from group g while
// staging {t+2,t+3} into group g^1 — ownership-disjoint, so NO sync inside the interval.
// Boundary = vmcnt(0) drain + one s_barrier per 2 tiles (publishes cross-wave).
// Open 2-tile region lets the compiler pipeline reads(t+1) under MFMA(t) and waves drift.
#define NT2 64   // 2048/32
__global__ __launch_bounds__(512, 2)
void k_gemm2_ww(const unsigned short* __restrict__ A,   // comb [8192][2048]
                const unsigned short* __restrict__ Bm,  // Wlb  [4096][2048]
                const float* __restrict__ bl,           // b_layers [4096]
                const float* __restrict__ c_cur,        // f32 [8192][1024]
                float* __restrict__ out) {              // h_next | c_next (f32)
  __shared__ __align__(16) unsigned short lds[4][16384];

  const int tid = threadIdx.x;
  const int lane = tid & 63;
  const int wid = tid >> 6;
  const int wr = wid >> 2;          // 0..1 : row half (128 rows)
  const int wc = wid & 3;           // 0..3 : col quarter (16 j x 4 gates)

  // L2-aware XCD mapping (R6)
  const int bid = blockIdx.x;
  const int xcd = bid & 7;
  const int ii = bid >> 3;
  const int sweep = ii >> 5;
  const int pos = ii & 31;
  const int bRow = xcd * 4 + sweep * 2 + (pos & 1);   // 0..31
  const int bCol = pos >> 1;                          // 0..15

  // ---- staging addresses (pre-swizzled global source; LDS dest linear) ----
  const int sr = tid >> 2;                 // 0..127
  const int swsel = (sr >> 1) & 3;
  const int gk = ((tid & 3) ^ swsel) << 3;
  const unsigned short* aBase = A + (long)(bRow * 256 + sr) * 2048 + gk;
  const int rl0 = sr, rl1 = 128 + sr;
  const int grow0 = ((rl0 >> 4) & 3) * 1024 + bCol * 64 + (rl0 >> 6) * 16 + (rl0 & 15);
  const int grow1 = ((rl1 >> 4) & 3) * 1024 + bCol * 64 + (rl1 >> 6) * 16 + (rl1 & 15);
  const unsigned short* bBase0 = Bm + (long)grow0 * 2048 + gk;
  const unsigned short* bBase1 = Bm + (long)grow1 * 2048 + gk;

#define STAGE_A2(slot, tt) { unsigned short* d_ = &lds[slot][0] + tid * 8;        \
    GLOAD16(aBase + (long)(tt) * 32, d_);                                          \
    GLOAD16(aBase + 128L * 2048 + (long)(tt) * 32, d_ + 512 * 8); }
#define STAGE_B2(slot, tt) { unsigned short* d_ = &lds[slot][8192] + tid * 8;     \
    GLOAD16(bBase0 + (long)(tt) * 32, d_);                                         \
    GLOAD16(bBase1 + (long)(tt) * 32, d_ + 512 * 8); }

  // ---- fragment read offsets (swizzled, 16-row-verified family), ushort units ----
  const int fr = lane & 15, q = lane >> 4;
  int offA[8], offB[4];
#pragma unroll
  for (int m = 0; m < 8; m++) {
    const int row = wr * 128 + m * 16 + fr;
    offA[m] = row * 32 + ((q ^ ((row >> 1) & 3)) << 3);
  }
#pragma unroll
  for (int n = 0; n < 4; n++) {
    const int row = wc * 64 + n * 16 + fr;
    offB[n] = 8192 + row * 32 + ((q ^ ((row >> 1) & 3)) << 3);
  }

  f32x4 acc[8][4] = {};   // [m][gate]

  // BODY(t, SLOT): no sync inside. Stages tile t+2 into slot SLOT^2 ((t+2)%4).
#define BODY(t, SLOT)                                                                \
  {                                                                                  \
    if ((t) + 2 < NT2) { STAGE_A2((SLOT) ^ 2, (t) + 2); STAGE_B2((SLOT) ^ 2, (t) + 2); } \
    const unsigned short* buf = &lds[SLOT][0];                                       \
    bf16x8 aF[8], bF[4];                                                             \
    _Pragma("unroll")                                                                \
    for (int n = 0; n < 4; n++) bF[n] = *(const bf16x8*)(buf + offB[n]);             \
    _Pragma("unroll")                                                                \
    for (int m = 0; m < 8; m++) aF[m] = *(const bf16x8*)(buf + offA[m]);             \
    __builtin_amdgcn_s_setprio(1);                                                   \
    _Pragma("unroll")                                                                \
    for (int m = 0; m < 8; m++)                                                      \
      _Pragma("unroll")                                                              \
      for (int n = 0; n < 4; n++)                                                    \
        acc[m][n] = __builtin_amdgcn_mfma_f32_16x16x32_bf16(aF[m], bF[n], acc[m][n], 0, 0, 0); \
    __builtin_amdgcn_s_setprio(0);                                                   \
  }
  // interval boundary: own-drain + publish. ONE per 2 tiles.
#define IBOUND() { asm volatile("s_waitcnt vmcnt(0)" ::: "memory"); __builtin_amdgcn_s_barrier(); }

  // ---- prologue: stage tiles 0,1 into slots 0,1; publish ----
  STAGE_A2(0, 0); STAGE_B2(0, 0);
  STAGE_A2(1, 1); STAGE_B2(1, 1);
  IBOUND();

  for (int ip = 0; ip < 16; ++ip) {
    const int t0 = ip * 4;
    BODY(t0,     0); BODY(t0 + 1, 1); IBOUND();
    BODY(t0 + 2, 2); BODY(t0 + 3, 3); IBOUND();
  }
#undef BODY
#undef IBOUND

  // ---- fused LSTM epilogue ----
  const int cr = (lane >> 4) * 4;
  const int cc = lane & 15;
  const int j = bCol * 64 + wc * 16 + cc;       // 0..1023
#pragma unroll
  for (int m = 0; m < 8; m++) {
#pragma unroll
    for (int r = 0; r < 4; r++) {
      const int row = bRow * 256 + wr * 128 + m * 16 + cr + r;
      float iv = sigm(acc[m][0][r] + bl[j]);
      float fv = sigm(acc[m][1][r] + bl[1024 + j]);
      float ov = sigm(acc[m][2][r] + bl[2048 + j]);
      float gv = tanhf(acc[m][3][r] + bl[3072 + j]);
      float cn = fv * c_cur[(long)row * HSZ + j] + iv * gv;
      float hn = ov * tanhf(cn);
      out[(long)row * HSZ + j] = hn;                         // h_next
      out[(long)B_ROWS * HSZ + (long)row * HSZ + j] = cn;    // c_next
    }
  }
}

// ---------- launch ----------
extern "C" void kernel_launch(void* const* d_in, const int* in_sizes, int n_in,
                              void* d_out, int out_size, void* d_ws, size_t ws_size,
                              hipStream_t stream) {
  const float* inp = (const float*)d_in[0];   // input_tensor [8192][1025]
  const float* h   = (const float*)d_in[1];   // h_cur
  const float* c   = (const float*)d_in[2];   // c_cur
  const float* Wl  = (const float*)d_in[3];   // W_layers [4096][2048]
  const float* bl  = (const float*)d_in[4];   // b_layers [4096]
  const float* Wd  = (const float*)d_in[5];   // W_desc [1024][1024]
  const float* bd  = (const float*)d_in[6];   // b_desc [1024]

  char* ws = (char*)d_ws;
  unsigned short* comb = (unsigned short*)(ws);               // 33,554,432 B
  unsigned short* Wlb  = (unsigned short*)(ws + 33554432);    // 16,777,216 B
  unsigned short* hb   = (unsigned short*)(ws + 50331648);    // 16,777,216 B
  unsigned short* Wdb  = (unsigned short*)(ws + 67108864);    //  2,097,152 B
  float*          Tm1  = (float*)(ws + 69206016);             //     32,768 B
  float*          out  = (float*)d_out;                       // f32 outputs

  hipLaunchKernelGGL(k_convert, dim3(2048), dim3(256), 0, stream,
                     inp, h, Wl, Wd, comb, Wlb, hb, Wdb, Tm1);
  hipLaunchKernelGGL(k_gemm1, dim3(64, 8), dim3(256), 0, stream,
                     hb, Wdb, h, bd, Tm1, comb);
  hipLaunchKernelGGL(k_gemm2_ww, dim3(512), dim3(512), 0, stream,
                     comb, Wlb, bl, c, out);
}